// Round 3
// baseline (518.889 us; speedup 1.0000x reference)
//
#include <hip/hip_runtime.h>
#include <math.h>

#define NB 32
#define NN 10000
#define DIM 256
#define NH 16
#define PREC 1028            // floats per partial record: l[4] + g[4][256]

// ---------------- kernel 0: detect mask dtype (int32 vs uint8) ----------------
__global__ void detect_mask_kernel(const int* mask_i, int* flag) {
    __shared__ int s;
    if (threadIdx.x == 0) s = 0;
    __syncthreads();
    int bad = 0;
    for (int i = threadIdx.x; i < 80000; i += 256) {
        unsigned v = (unsigned)mask_i[i];
        if (v > 1u) bad = 1;
    }
    if (bad) s = 1;            // benign race: same value
    __syncthreads();
    if (threadIdx.x == 0) *flag = s;
}

// ---------------- kernel 1: per-batch w~ = (1/4) * (ctx@Wq^T)_head @ Wk_block --
__global__ void prep_kernel(const float* __restrict__ ctx,
                            const float* __restrict__ Wq,
                            const float* __restrict__ Wk,
                            float* __restrict__ wt) {
    int b = blockIdx.x;
    int t = threadIdx.x, lane = t & 63, w = t >> 6;
    __shared__ float ctxL[DIM];
    __shared__ float qL[DIM];
    ctxL[t] = ctx[b * DIM + t];
    __syncthreads();

    float4 c = ((const float4*)ctxL)[lane];
    for (int i = w; i < DIM; i += 4) {
        float4 wq = ((const float4*)(Wq + (size_t)i * DIM))[lane];
        float s = wq.x * c.x + wq.y * c.y + wq.z * c.z + wq.w * c.w;
        #pragma unroll
        for (int off = 1; off < 64; off <<= 1) s += __shfl_xor(s, off, 64);
        if (lane == 0) qL[i] = s;
    }
    __syncthreads();

    for (int h = 0; h < NH; ++h) {
        float a = 0.f;
        #pragma unroll
        for (int j = 0; j < 16; ++j)
            a += qL[h * 16 + j] * Wk[(size_t)(h * 16 + j) * DIM + t];
        wt[((size_t)b * NH + h) * DIM + t] = 0.25f * a;
    }
}

// ---------------- kernel 2: fused logits + exp + accumulate ------------------
// One block = (batch b, partition). Wave w owns heads 4w..4w+3. BRANCH-FREE
// inner loop: x loaded unconditionally, p multiplied by mask -> compiler can
// software-pipeline the loads (no data-dependent branch blocking prefetch).
__launch_bounds__(256, 8)
__global__ void attend_kernel(const float* __restrict__ node,
                              const void* __restrict__ maskp,
                              const float* __restrict__ wt,
                              float* __restrict__ partials,
                              const int* __restrict__ flag,
                              int lgnp, int psz) {
    int npart = 1 << lgnp;
    int b = blockIdx.x >> lgnp;
    int part = blockIdx.x & (npart - 1);
    int lane = threadIdx.x & 63, w = threadIdx.x >> 6;
    const bool bytemask = (*flag != 0);

    float4 w0 = ((const float4*)(wt + ((size_t)b * NH + 4 * w + 0) * DIM))[lane];
    float4 w1 = ((const float4*)(wt + ((size_t)b * NH + 4 * w + 1) * DIM))[lane];
    float4 w2 = ((const float4*)(wt + ((size_t)b * NH + 4 * w + 2) * DIM))[lane];
    float4 w3 = ((const float4*)(wt + ((size_t)b * NH + 4 * w + 3) * DIM))[lane];

    float4 g0 = make_float4(0.f,0.f,0.f,0.f), g1 = g0, g2 = g0, g3 = g0;
    float l0 = 0.f, l1 = 0.f, l2 = 0.f, l3 = 0.f;

    int n0 = part * psz;
    int n1 = n0 + psz; if (n1 > NN) n1 = NN;
    const float* nb = node + (size_t)b * NN * DIM;
    const unsigned char* m8 = (const unsigned char*)maskp + (size_t)b * NN;
    const int* m32 = (const int*)maskp + (size_t)b * NN;

    auto run = [&](auto mp) {
        #pragma unroll 4
        for (int n = n0; n < n1; ++n) {
            float mv = (float)mp[n];
            float4 x = ((const float4*)(nb + (size_t)n * DIM))[lane];

            float s0 = x.x*w0.x + x.y*w0.y + x.z*w0.z + x.w*w0.w;
            float s1 = x.x*w1.x + x.y*w1.y + x.z*w1.z + x.w*w1.w;
            float s2 = x.x*w2.x + x.y*w2.y + x.z*w2.z + x.w*w2.w;
            float s3 = x.x*w3.x + x.y*w3.y + x.z*w3.z + x.w*w3.w;
            #pragma unroll
            for (int off = 1; off < 64; off <<= 1) {
                s0 += __shfl_xor(s0, off, 64);
                s1 += __shfl_xor(s1, off, 64);
                s2 += __shfl_xor(s2, off, 64);
                s3 += __shfl_xor(s3, off, 64);
            }
            // logits ~N(0,1): exp safe in fp32; mask applied as 0/1 multiplier
            float p0 = mv * __expf(s0), p1 = mv * __expf(s1);
            float p2 = mv * __expf(s2), p3 = mv * __expf(s3);
            l0 += p0; l1 += p1; l2 += p2; l3 += p3;
            g0.x += p0*x.x; g0.y += p0*x.y; g0.z += p0*x.z; g0.w += p0*x.w;
            g1.x += p1*x.x; g1.y += p1*x.y; g1.z += p1*x.z; g1.w += p1*x.w;
            g2.x += p2*x.x; g2.y += p2*x.y; g2.z += p2*x.z; g2.w += p2*x.w;
            g3.x += p3*x.x; g3.y += p3*x.y; g3.z += p3*x.z; g3.w += p3*x.w;
        }
    };
    if (bytemask) run(m8); else run(m32);

    float* pout = partials + (size_t)(((b << lgnp) + part) * 4 + w) * PREC;
    if (lane == 0) { pout[0] = l0; pout[1] = l1; pout[2] = l2; pout[3] = l3; }
    ((float4*)(pout + 4 + 0*256))[lane] = g0;
    ((float4*)(pout + 4 + 1*256))[lane] = g1;
    ((float4*)(pout + 4 + 2*256))[lane] = g2;
    ((float4*)(pout + 4 + 3*256))[lane] = g3;
}

// ---------------- kernel 3a: parallel partial-merge --------------------------
// grid = NB*16 blocks; block (b,c): 256 threads each sum one (h,d) element
// over all partitions. Coalesced (consecutive t -> consecutive d).
__global__ void reduce_kernel(const float* __restrict__ partials,
                              float* __restrict__ gred,
                              float* __restrict__ lred, int lgnp) {
    int npart = 1 << lgnp;
    int b = blockIdx.x >> 4;
    int c = blockIdx.x & 15;
    int e = c * 256 + threadIdx.x;     // 0..4095 = h*256+d
    int h = e >> 8, d = e & 255;
    const float* pb = partials + ((size_t)(b << lgnp) * 4) * PREC;
    float a = 0.f;
    for (int p = 0; p < npart; ++p)
        a += pb[(size_t)(p * 4 + (h >> 2)) * PREC + 4 + (h & 3) * 256 + d];
    gred[((size_t)b * NH + h) * DIM + d] = a;
    if (c == 0 && threadIdx.x < NH) {
        int hh = threadIdx.x;
        float la = 0.f;
        for (int p = 0; p < npart; ++p)
            la += pb[(size_t)(p * 4 + (hh >> 2)) * PREC + (hh & 3)];
        lred[(size_t)b * NH + hh] = la;
    }
}

// ---------------- kernel 3b: fold Wv and Wo ----------------------------------
__global__ void output_kernel(const float* __restrict__ gred,
                              const float* __restrict__ lred,
                              const float* __restrict__ Wv,
                              const float* __restrict__ Wo,
                              float* __restrict__ out) {
    int b = blockIdx.x, t = threadIdx.x;
    __shared__ float gs[NH * DIM];
    __shared__ float hc[DIM];
    __shared__ float ls[NH];
    for (int i = t; i < NH * DIM; i += 256) gs[i] = gred[(size_t)b * NH * DIM + i];
    if (t < NH) ls[t] = lred[b * NH + t];
    __syncthreads();

    int h = t >> 4;
    const float4* wrow = (const float4*)(Wv + (size_t)t * DIM);
    const float4* grow = (const float4*)(gs + h * DIM);
    float a = 0.f;
    #pragma unroll 8
    for (int d4 = 0; d4 < 64; ++d4) {
        float4 wv = wrow[d4]; float4 gv = grow[d4];
        a += wv.x*gv.x + wv.y*gv.y + wv.z*gv.z + wv.w*gv.w;
    }
    hc[t] = a / ls[h];
    __syncthreads();

    const float4* worow = (const float4*)(Wo + (size_t)t * DIM);
    float o = 0.f;
    #pragma unroll 8
    for (int i4 = 0; i4 < 64; ++i4) {
        float4 wv = worow[i4]; float4 hv = ((const float4*)hc)[i4];
        o += wv.x*hv.x + wv.y*hv.y + wv.z*hv.z + wv.w*hv.w;
    }
    out[(size_t)b * DIM + t] = o;
}

extern "C" void kernel_launch(void* const* d_in, const int* in_sizes, int n_in,
                              void* d_out, int out_size, void* d_ws, size_t ws_size,
                              hipStream_t stream) {
    const float* ctx  = (const float*)d_in[0];
    const float* node = (const float*)d_in[1];
    const void*  mask = (const void*)d_in[2];
    const float* Wq   = (const float*)d_in[3];
    const float* Wk   = (const float*)d_in[4];
    const float* Wv   = (const float*)d_in[5];
    const float* Wo   = (const float*)d_in[6];
    float* out = (float*)d_out;

    // ws layout (floats): flag/pad 256 | wt 32*16*256 | gred 32*16*256 | lred 512 | partials
    const size_t FIX = 256 + (size_t)NB*NH*DIM + (size_t)NB*NH*DIM + 512;
    int lgnp = 6;  // npart=64 -> 2048 blocks (8/CU, 32 waves/CU)
    while (lgnp > 4) {
        size_t need = (FIX + (size_t)NB * ((size_t)1 << lgnp) * 4 * PREC) * 4;
        if (need <= ws_size) break;
        --lgnp;
    }
    int npart = 1 << lgnp;
    int psz = (NN + npart - 1) / npart;

    float* wsf = (float*)d_ws;
    int*   flag = (int*)d_ws;
    float* wt = wsf + 256;
    float* gred = wt + (size_t)NB * NH * DIM;
    float* lred = gred + (size_t)NB * NH * DIM;
    float* partials = lred + 512;

    detect_mask_kernel<<<1, 256, 0, stream>>>((const int*)mask, flag);
    prep_kernel<<<NB, 256, 0, stream>>>(ctx, Wq, Wk, wt);
    attend_kernel<<<NB * npart, 256, 0, stream>>>(node, mask, wt, partials, flag, lgnp, psz);
    reduce_kernel<<<NB * 16, 256, 0, stream>>>(partials, gred, lred, lgnp);
    output_kernel<<<NB, 256, 0, stream>>>(gred, lred, Wv, Wo, out);
}

// Round 5
// 232.427 us; speedup vs baseline: 2.2325x; 2.2325x over previous
//
#include <hip/hip_runtime.h>
#include <math.h>

#define NB 32
#define NN 10000
#define DIM 256
#define NH 16
#define PREC2 4112   // per-block partial: l[16] + g[16*256]

// ---- bf16 helpers (pack with round-to-nearest-even, unpack via shift) ------
__device__ __forceinline__ unsigned bf16rne(float f) {
    unsigned u = __float_as_uint(f);
    return (u + 0x7FFFu + ((u >> 16) & 1u)) >> 16;
}
__device__ __forceinline__ unsigned pack2(float a, float b) {
    return bf16rne(a) | (bf16rne(b) << 16);
}
__device__ __forceinline__ float blo(unsigned u) { return __uint_as_float(u << 16); }
__device__ __forceinline__ float bhi(unsigned u) { return __uint_as_float(u & 0xFFFF0000u); }
__device__ __forceinline__ float rdlane(float v, int n) {
    return __uint_as_float((unsigned)__builtin_amdgcn_readlane((int)__float_as_uint(v), n));
}
// XOR-swizzle: permute 16B blocks within each 128B group (flips bits 4-6);
// write path and BOTH read paths use the same XOR -> bijective & consistent.
#define SWZ(row, byte) ((byte) ^ (((row) & 7) << 4))

// ---------------- kernel 0: detect mask dtype (int32 vs uint8), parallel ----
__global__ void detect_mask_kernel(const int* mask_i, int* flag) {
    int bad = 0;
    for (int i = blockIdx.x * 256 + threadIdx.x; i < 80000; i += gridDim.x * 256)
        if ((unsigned)mask_i[i] > 1u) bad = 1;
    if (bad) atomicOr(flag, 1);   // deterministic final value
}

// ---------------- kernel 1: per-batch w~ = (1/4) * (ctx@Wq^T)_head @ Wk_block
__global__ void prep_kernel(const float* __restrict__ ctx,
                            const float* __restrict__ Wq,
                            const float* __restrict__ Wk,
                            float* __restrict__ wt) {
    int b = blockIdx.x;
    int t = threadIdx.x, lane = t & 63, w = t >> 6;
    __shared__ float ctxL[DIM];
    __shared__ float qL[DIM];
    ctxL[t] = ctx[b * DIM + t];
    __syncthreads();

    float4 c = ((const float4*)ctxL)[lane];
    for (int i = w; i < DIM; i += 4) {
        float4 wq = ((const float4*)(Wq + (size_t)i * DIM))[lane];
        float s = wq.x * c.x + wq.y * c.y + wq.z * c.z + wq.w * c.w;
        #pragma unroll
        for (int off = 1; off < 64; off <<= 1) s += __shfl_xor(s, off, 64);
        if (lane == 0) qL[i] = s;
    }
    __syncthreads();

    for (int h = 0; h < NH; ++h) {
        float a = 0.f;
        #pragma unroll
        for (int j = 0; j < 16; ++j)
            a += qL[h * 16 + j] * Wk[(size_t)(h * 16 + j) * DIM + t];
        wt[((size_t)b * NH + h) * DIM + t] = 0.25f * a;
    }
}

// ---------------- kernel 2: fused single-pass attend (LDS transpose) --------
// Block = (b, part). Per 64-node tile:
//   stage: coalesced global float4 -> bf16 -> swizzled LDS rows (512B/row)
//          (8 x 16B per thread = full 128B quarter -- the round-4 bug was 4)
//   phase A: lane=node, wave owns 4 heads; dot via swizzled b128 LDS row-reads
//            x wave-uniform w rows -> s[4]; p = mask * exp(s). NO reduction.
//   phase B: lane=d4; p broadcast via v_readlane (SGPR pipe); g[4]x4 in regs.
// Waves own disjoint heads -> no merge; block writes one partial record.
__launch_bounds__(256, 4)
__global__ void attend_kernel(const float* __restrict__ node,
                              const void* __restrict__ maskp,
                              const float* __restrict__ wt,
                              float* __restrict__ partials,
                              const int* __restrict__ flag,
                              int lgnp, int psz) {
    __shared__ unsigned xs[64 * 128];   // 64 rows x 256 bf16 (512B/row) = 32KB
    int npart = 1 << lgnp;
    int b = blockIdx.x >> lgnp;
    int part = blockIdx.x & (npart - 1);
    int t = threadIdx.x, lane = t & 63;
    int wu = __builtin_amdgcn_readfirstlane(t >> 6);
    const bool bytemask = (*flag != 0);

    int n0 = part * psz;
    int n1 = n0 + psz; if (n1 > NN) n1 = NN;
    const float* nb = node + (size_t)b * NN * DIM;
    const unsigned char* m8 = (const unsigned char*)maskp + (size_t)b * NN;
    const int* m32 = (const int*)maskp + (size_t)b * NN;

    // wave-uniform w~ row pointers (SGPR)
    const float* w0r = wt + ((size_t)b * NH + 4 * wu + 0) * DIM;
    const float* w1r = wt + ((size_t)b * NH + 4 * wu + 1) * DIM;
    const float* w2r = wt + ((size_t)b * NH + 4 * wu + 2) * DIM;
    const float* w3r = wt + ((size_t)b * NH + 4 * wu + 3) * DIM;

    float4 g0 = make_float4(0.f,0.f,0.f,0.f), g1 = g0, g2 = g0, g3 = g0;
    float l0 = 0.f, l1 = 0.f, l2 = 0.f, l3 = 0.f;

    char* lds = (char*)xs;
    int sr = t >> 2, sq = t & 3;     // staging role: row, 64-float quarter

    for (int tb = n0; tb < n1; tb += 64) {
        __syncthreads();             // previous tile's phase B done
        {   // ---- stage: 64 rows fp32 -> bf16 -> LDS; 8 x 16B = full 128B ----
            int ni = tb + sr; if (ni >= NN) ni = NN - 1;   // clamp; p=0 kills it
            const float4* src = (const float4*)(nb + (size_t)ni * DIM + sq * 64);
            char* dst = lds + sr * 512;
            #pragma unroll
            for (int i = 0; i < 8; ++i) {
                float4 A = src[2*i], B = src[2*i+1];
                uint4 pk = make_uint4(pack2(A.x,A.y), pack2(A.z,A.w),
                                      pack2(B.x,B.y), pack2(B.z,B.w));
                *(uint4*)(dst + SWZ(sr, sq*128 + i*16)) = pk;
            }
        }
        __syncthreads();             // tile ready

        // ---- phase A: lane = node ----
        float mv = 0.f;
        {   int ni = tb + lane;
            if (ni < n1) mv = bytemask ? (float)m8[ni] : (float)(m32[ni] != 0); }
        float s0 = 0.f, s1 = 0.f, s2 = 0.f, s3 = 0.f;
        const char* lrow = lds + lane * 512;
        #pragma unroll 4
        for (int c = 0; c < 32; ++c) {
            uint4 xv = *(const uint4*)(lrow + SWZ(lane, c*16));
            float x0=blo(xv.x), x1=bhi(xv.x), x2=blo(xv.y), x3=bhi(xv.y);
            float x4=blo(xv.z), x5=bhi(xv.z), x6=blo(xv.w), x7=bhi(xv.w);
            #define DOT8(S, WR) { \
                float4 A = *(const float4*)((WR) + 8*c); \
                float4 Bq = *(const float4*)((WR) + 8*c + 4); \
                S += x0*A.x + x1*A.y + x2*A.z + x3*A.w \
                   + x4*Bq.x + x5*Bq.y + x6*Bq.z + x7*Bq.w; }
            DOT8(s0, w0r) DOT8(s1, w1r) DOT8(s2, w2r) DOT8(s3, w3r)
            #undef DOT8
        }
        // logits ~N(0,1): exp safe in fp32; mask as 0/1 multiplier
        float p0 = mv * __expf(s0), p1 = mv * __expf(s1);
        float p2 = mv * __expf(s2), p3 = mv * __expf(s3);

        // ---- phase B: lane = d4 (d = 4*lane..4*lane+3) ----
        #pragma unroll 2
        for (int n = 0; n < 64; ++n) {
            float q0 = rdlane(p0, n), q1 = rdlane(p1, n);
            float q2 = rdlane(p2, n), q3 = rdlane(p3, n);
            uint2 xv = *(const uint2*)(lds + n*512 + SWZ(n, lane*8));
            float x0 = blo(xv.x), x1 = bhi(xv.x), x2 = blo(xv.y), x3 = bhi(xv.y);
            g0.x += q0*x0; g0.y += q0*x1; g0.z += q0*x2; g0.w += q0*x3;
            g1.x += q1*x0; g1.y += q1*x1; g1.z += q1*x2; g1.w += q1*x3;
            g2.x += q2*x0; g2.y += q2*x1; g2.z += q2*x2; g2.w += q2*x3;
            g3.x += q3*x0; g3.y += q3*x1; g3.z += q3*x2; g3.w += q3*x3;
            l0 += q0; l1 += q1; l2 += q2; l3 += q3;
        }
    }

    // ---- write per-block partial record (waves own disjoint heads) ----
    float* rec = partials + (size_t)blockIdx.x * PREC2;
    if (lane == 0) {
        rec[4*wu+0] = l0; rec[4*wu+1] = l1; rec[4*wu+2] = l2; rec[4*wu+3] = l3;
    }
    ((float4*)(rec + 16 + (size_t)(4*wu+0) * DIM))[lane] = g0;
    ((float4*)(rec + 16 + (size_t)(4*wu+1) * DIM))[lane] = g1;
    ((float4*)(rec + 16 + (size_t)(4*wu+2) * DIM))[lane] = g2;
    ((float4*)(rec + 16 + (size_t)(4*wu+3) * DIM))[lane] = g3;
}

// ---------------- kernel 3a: merge partials (coalesced) ---------------------
__global__ void reduce_kernel(const float* __restrict__ partials,
                              float* __restrict__ gred,
                              float* __restrict__ lred, int lgnp) {
    int npart = 1 << lgnp;
    int b = blockIdx.x >> 4, c = blockIdx.x & 15;
    int e = c * 256 + threadIdx.x;            // h*256 + d
    const float* pb = partials + ((size_t)b << lgnp) * PREC2;
    float a = 0.f;
    for (int p = 0; p < npart; ++p) a += pb[(size_t)p * PREC2 + 16 + e];
    gred[(size_t)b * (NH * DIM) + e] = a;
    if (c == 0 && threadIdx.x < NH) {
        float la = 0.f;
        for (int p = 0; p < npart; ++p) la += pb[(size_t)p * PREC2 + threadIdx.x];
        lred[b * NH + threadIdx.x] = la;
    }
}

// ---------------- kernel 3b: fold Wv and Wo ---------------------------------
__global__ void output_kernel(const float* __restrict__ gred,
                              const float* __restrict__ lred,
                              const float* __restrict__ Wv,
                              const float* __restrict__ Wo,
                              float* __restrict__ out) {
    int b = blockIdx.x, t = threadIdx.x;
    __shared__ float gs[NH * DIM];
    __shared__ float hc[DIM];
    __shared__ float ls[NH];
    for (int i = t; i < NH * DIM; i += 256) gs[i] = gred[(size_t)b * NH * DIM + i];
    if (t < NH) ls[t] = lred[b * NH + t];
    __syncthreads();

    int h = t >> 4;
    const float4* wrow = (const float4*)(Wv + (size_t)t * DIM);
    const float4* grow = (const float4*)(gs + h * DIM);
    float a = 0.f;
    #pragma unroll 8
    for (int d4 = 0; d4 < 64; ++d4) {
        float4 wv = wrow[d4]; float4 gv = grow[d4];
        a += wv.x*gv.x + wv.y*gv.y + wv.z*gv.z + wv.w*gv.w;
    }
    hc[t] = a / ls[h];
    __syncthreads();

    const float4* worow = (const float4*)(Wo + (size_t)t * DIM);
    float o = 0.f;
    #pragma unroll 8
    for (int i4 = 0; i4 < 64; ++i4) {
        float4 wv = worow[i4]; float4 hv = ((const float4*)hc)[i4];
        o += wv.x*hv.x + wv.y*hv.y + wv.z*hv.z + wv.w*hv.w;
    }
    out[(size_t)b * DIM + t] = o;
}

extern "C" void kernel_launch(void* const* d_in, const int* in_sizes, int n_in,
                              void* d_out, int out_size, void* d_ws, size_t ws_size,
                              hipStream_t stream) {
    const float* ctx  = (const float*)d_in[0];
    const float* node = (const float*)d_in[1];
    const void*  mask = (const void*)d_in[2];
    const float* Wq   = (const float*)d_in[3];
    const float* Wk   = (const float*)d_in[4];
    const float* Wv   = (const float*)d_in[5];
    const float* Wo   = (const float*)d_in[6];
    float* out = (float*)d_out;

    // ws floats: flag/pad 256 | wt 131072 | gred 131072 | lred 512 | partials
    const size_t FIX = 256 + (size_t)NB*NH*DIM * 2 + 512;
    int lgnp = 5;  // npart=32 -> 1024 blocks (4/CU, 32KB LDS each)
    {
        size_t need = (FIX + (size_t)NB * 32 * PREC2) * 4;
        if (ws_size < need) lgnp = 4;   // npart=16 fallback (~8.8MB)
    }
    int npart = 1 << lgnp;
    int psz = (NN + npart - 1) / npart;

    float* wsf = (float*)d_ws;
    int*   flag = (int*)d_ws;
    float* wt = wsf + 256;
    float* gred = wt + (size_t)NB * NH * DIM;
    float* lred = gred + (size_t)NB * NH * DIM;
    float* partials = lred + 512;

    hipMemsetAsync(flag, 0, 4, stream);
    detect_mask_kernel<<<64, 256, 0, stream>>>((const int*)mask, flag);
    prep_kernel<<<NB, 256, 0, stream>>>(ctx, Wq, Wk, wt);
    attend_kernel<<<NB * npart, 256, 0, stream>>>(node, mask, wt, partials, flag, lgnp, psz);
    reduce_kernel<<<NB * 16, 256, 0, stream>>>(partials, gred, lred, lgnp);
    output_kernel<<<NB, 256, 0, stream>>>(gred, lred, Wv, Wo, out);
}

// Round 6
// 178.553 us; speedup vs baseline: 2.9061x; 1.3017x over previous
//
#include <hip/hip_runtime.h>
#include <math.h>

#define NB 32
#define NN 10000
#define DIM 256
#define NH 16
#define PREC2 4112   // per-block partial: l[16] + g[16*256]

typedef short short8v __attribute__((ext_vector_type(8)));
typedef float float4v __attribute__((ext_vector_type(4)));

// ---- bf16 helpers (RNE pack) ----
__device__ __forceinline__ unsigned bf16rne(float f) {
    unsigned u = __float_as_uint(f);
    return (u + 0x7FFFu + ((u >> 16) & 1u)) >> 16;
}
__device__ __forceinline__ unsigned pack2(float a, float b) {
    return bf16rne(a) | (bf16rne(b) << 16);
}
__device__ __forceinline__ short8v pack8(float4 A, float4 B) {
    union { short8v s; unsigned u[4]; } r;
    r.u[0] = pack2(A.x, A.y); r.u[1] = pack2(A.z, A.w);
    r.u[2] = pack2(B.x, B.y); r.u[3] = pack2(B.z, B.w);
    return r.s;
}
// row-parity XOR swizzle for x_T (128B rows): spreads row-strided b128 across banks
#define SWB(d) ((((d) >> 1) & 7) << 4)

// ---------------- kernel 0: detect mask dtype (int32 vs uint8) --------------
__global__ void detect_mask_kernel(const int* mask_i, int* flag) {
    int bad = 0;
    for (int i = blockIdx.x * 256 + threadIdx.x; i < 80000; i += gridDim.x * 256)
        if ((unsigned)mask_i[i] > 1u) bad = 1;
    if (bad) atomicOr(flag, 1);
}

// ---------------- kernel 1: per-batch w~ = (1/4) * (ctx@Wq^T)_head @ Wk_block
__global__ void prep_kernel(const float* __restrict__ ctx,
                            const float* __restrict__ Wq,
                            const float* __restrict__ Wk,
                            float* __restrict__ wt) {
    int b = blockIdx.x;
    int t = threadIdx.x, lane = t & 63, w = t >> 6;
    __shared__ float ctxL[DIM];
    __shared__ float qL[DIM];
    ctxL[t] = ctx[b * DIM + t];
    __syncthreads();

    float4 c = ((const float4*)ctxL)[lane];
    for (int i = w; i < DIM; i += 4) {
        float4 wq = ((const float4*)(Wq + (size_t)i * DIM))[lane];
        float s = wq.x * c.x + wq.y * c.y + wq.z * c.z + wq.w * c.w;
        #pragma unroll
        for (int off = 1; off < 64; off <<= 1) s += __shfl_xor(s, off, 64);
        if (lane == 0) qL[i] = s;
    }
    __syncthreads();

    for (int h = 0; h < NH; ++h) {
        float a = 0.f;
        #pragma unroll
        for (int j = 0; j < 16; ++j)
            a += qL[h * 16 + j] * Wk[(size_t)(h * 16 + j) * DIM + t];
        wt[((size_t)b * NH + h) * DIM + t] = 0.25f * a;
    }
}

// ---------------- kernel 2: MFMA attend -------------------------------------
// Per 64-node tile:
//  stage: coalesced float2 reads -> bf16 -> x_T[d][node] LDS (swizzled rows)
//  phase A (per wave = 16 nodes): S = X.W~^T via 8x mfma_16x16x32_bf16;
//           A-frags packed from global (L1/L2 hits), B-frags = w~ hoisted once.
//           p = mask*exp(S) directly in D-layout; l via 2 shfl; P -> LDS [h][node].
//  phase B (per wave = 64 d-cols, swapped): G^T = X^T . P^T via 8x MFMA;
//           A = x_T (b128, swizzled), B = P (b128). acc persists in VGPRs.
__launch_bounds__(256, 4)
__global__ void attend_kernel(const float* __restrict__ node,
                              const void* __restrict__ maskp,
                              const float* __restrict__ wt,
                              float* __restrict__ partials,
                              const int* __restrict__ flag,
                              int lgnp, int psz) {
    __shared__ __align__(16) char smem[35328];  // x_T 32768 | P 2304 | l 256
    char* XT = smem;
    char* PL = smem + 32768;
    float* LL = (float*)(smem + 35072);

    int npart = 1 << lgnp;
    int b = blockIdx.x >> lgnp;
    int part = blockIdx.x & (npart - 1);
    int t = threadIdx.x, lane = t & 63;
    int w = __builtin_amdgcn_readfirstlane(t >> 6);
    int hq = lane & 15, g = lane >> 4;          // MFMA row/col index, k-group
    const bool bytemask = (*flag != 0);

    int n0 = part * psz;
    int n1 = n0 + psz; if (n1 > NN) n1 = NN;
    const float* nb = node + (size_t)b * NN * DIM;
    const unsigned char* m8 = (const unsigned char*)maskp + (size_t)b * NN;
    const int* m32 = (const int*)maskp + (size_t)b * NN;

    // ---- hoist w~ B-fragments for all 8 k-chunks (once per block) ----
    short8v wfrag[8];
    {
        const float* wrow = wt + ((size_t)b * NH + hq) * DIM + g * 8;
        #pragma unroll
        for (int cc = 0; cc < 8; ++cc) {
            float4 A = *(const float4*)(wrow + cc * 32);
            float4 B = *(const float4*)(wrow + cc * 32 + 4);
            wfrag[cc] = pack8(A, B);
        }
    }

    float4v accB[4];
    #pragma unroll
    for (int m = 0; m < 4; ++m) accB[m] = (float4v){0.f, 0.f, 0.f, 0.f};
    float lacc = 0.f;

    // staging role: even d-row + parity, n-half
    int sd = (w & 1) * 128 + 2 * lane;          // 0..254 even
    int shb = (w >> 1) * 32;                    // node-half base
    unsigned sswz = SWB(sd);

    for (int tb = n0; tb < n1; tb += 64) {
        __syncthreads();   // prev phase B done: XT/PL reusable

        // ---- stage: x[tb..tb+63][:] -> bf16 x_T[d][node] (transposed) ----
        #pragma unroll
        for (int j = 0; j < 32; j += 8) {
            unsigned r0[4], r1[4];
            #pragma unroll
            for (int i = 0; i < 8; i += 2) {
                int nA = tb + shb + j + i;
                int nB = nA + 1;
                if (nA > NN - 1) nA = NN - 1;
                if (nB > NN - 1) nB = NN - 1;
                float2 vA = *(const float2*)(nb + (size_t)nA * DIM + sd);
                float2 vB = *(const float2*)(nb + (size_t)nB * DIM + sd);
                r0[i >> 1] = pack2(vA.x, vB.x);   // row sd,   nodes ascending
                r1[i >> 1] = pack2(vA.y, vB.y);   // row sd+1
            }
            unsigned nb2 = ((shb + j) * 2) ^ sswz;
            *(uint4*)(XT + sd * 128 + nb2)       = make_uint4(r0[0], r0[1], r0[2], r0[3]);
            *(uint4*)(XT + (sd + 1) * 128 + nb2) = make_uint4(r1[0], r1[1], r1[2], r1[3]);
        }

        // ---- phase A: S = X . W~^T for this wave's 16 nodes ----
        float4v acc = (float4v){0.f, 0.f, 0.f, 0.f};
        {
            int anode = tb + 16 * w + hq;
            if (anode > NN - 1) anode = NN - 1;
            const float* arow = nb + (size_t)anode * DIM + g * 8;
            #pragma unroll
            for (int cc = 0; cc < 8; ++cc) {
                float4 A = *(const float4*)(arow + cc * 32);
                float4 B = *(const float4*)(arow + cc * 32 + 4);
                short8v af = pack8(A, B);
                acc = __builtin_amdgcn_mfma_f32_16x16x32_bf16(af, wfrag[cc], acc, 0, 0, 0);
            }
        }
        // mask + exp ; D-layout: lane holds head hq, nodes (g*4 + r)
        int mb = tb + 16 * w + 4 * g;
        float mv0, mv1, mv2, mv3;
        {
            int mc = mb > NN - 4 ? NN - 4 : mb;
            if (bytemask) {
                uchar4 mm = *(const uchar4*)(m8 + mc);
                mv0 = mm.x; mv1 = mm.y; mv2 = mm.z; mv3 = mm.w;
            } else {
                int4 mm = *(const int4*)(m32 + mc);
                mv0 = (mm.x != 0); mv1 = (mm.y != 0); mv2 = (mm.z != 0); mv3 = (mm.w != 0);
            }
        }
        if (mb + 0 >= n1) mv0 = 0.f;
        if (mb + 1 >= n1) mv1 = 0.f;
        if (mb + 2 >= n1) mv2 = 0.f;
        if (mb + 3 >= n1) mv3 = 0.f;
        // logits ~N(0,1): exp safe in fp32
        float p0 = mv0 * __expf(acc[0]);
        float p1 = mv1 * __expf(acc[1]);
        float p2 = mv2 * __expf(acc[2]);
        float p3 = mv3 * __expf(acc[3]);
        float ts = p0 + p1 + p2 + p3;
        ts += __shfl_xor(ts, 16, 64);
        ts += __shfl_xor(ts, 32, 64);
        lacc += ts;                                // per-lane: l[head hq] partial
        // P_lds[h][node] bf16, row pad 144B
        *(uint2*)(PL + hq * 144 + (16 * w + 4 * g) * 2) =
            make_uint2(pack2(p0, p1), pack2(p2, p3));

        __syncthreads();   // XT + PL ready

        // ---- phase B: G^T[d][h] += X^T . P^T ; wave owns d = 64w..64w+63 ----
        #pragma unroll
        for (int chunk = 0; chunk < 2; ++chunk) {
            short8v pf = *(const short8v*)(PL + hq * 144 + chunk * 64 + g * 16);
            #pragma unroll
            for (int m = 0; m < 4; ++m) {
                int d = 64 * w + 16 * m + hq;
                short8v xf = *(const short8v*)(XT + d * 128 + ((chunk * 64 + g * 16) ^ SWB(d)));
                accB[m] = __builtin_amdgcn_mfma_f32_16x16x32_bf16(xf, pf, accB[m], 0, 0, 0);
            }
        }
    }

    // ---- epilogue: bounce G through LDS for coalesced partial write ----
    __syncthreads();
    float* GL = (float*)smem;                      // [16][260] f32, reuses XT
    #pragma unroll
    for (int m = 0; m < 4; ++m) {
        #pragma unroll
        for (int r = 0; r < 4; ++r)
            GL[hq * 260 + 64 * w + 16 * m + 4 * g + r] = accB[m][r];
    }
    if (lane < 16) LL[w * 16 + lane] = lacc;
    __syncthreads();

    float* rec = partials + (size_t)blockIdx.x * PREC2;
    if (t < NH) rec[t] = LL[t] + LL[16 + t] + LL[32 + t] + LL[48 + t];
    for (int i = t; i < NH * DIM; i += 256)
        rec[16 + i] = GL[(i >> 8) * 260 + (i & 255)];
}

// ---------------- kernel 3a: merge partials (coalesced) ---------------------
__global__ void reduce_kernel(const float* __restrict__ partials,
                              float* __restrict__ gred,
                              float* __restrict__ lred, int lgnp) {
    int npart = 1 << lgnp;
    int b = blockIdx.x >> 4, c = blockIdx.x & 15;
    int e = c * 256 + threadIdx.x;            // h*256 + d
    const float* pb = partials + ((size_t)b << lgnp) * PREC2;
    float a = 0.f;
    for (int p = 0; p < npart; ++p) a += pb[(size_t)p * PREC2 + 16 + e];
    gred[(size_t)b * (NH * DIM) + e] = a;
    if (c == 0 && threadIdx.x < NH) {
        float la = 0.f;
        for (int p = 0; p < npart; ++p) la += pb[(size_t)p * PREC2 + threadIdx.x];
        lred[b * NH + threadIdx.x] = la;
    }
}

// ---------------- kernel 3b: fold Wv and Wo ---------------------------------
__global__ void output_kernel(const float* __restrict__ gred,
                              const float* __restrict__ lred,
                              const float* __restrict__ Wv,
                              const float* __restrict__ Wo,
                              float* __restrict__ out) {
    int b = blockIdx.x, t = threadIdx.x;
    __shared__ float gs[NH * DIM];
    __shared__ float hc[DIM];
    __shared__ float ls[NH];
    for (int i = t; i < NH * DIM; i += 256) gs[i] = gred[(size_t)b * NH * DIM + i];
    if (t < NH) ls[t] = lred[b * NH + t];
    __syncthreads();

    int h = t >> 4;
    const float4* wrow = (const float4*)(Wv + (size_t)t * DIM);
    const float4* grow = (const float4*)(gs + h * DIM);
    float a = 0.f;
    #pragma unroll 8
    for (int d4 = 0; d4 < 64; ++d4) {
        float4 wv = wrow[d4]; float4 gv = grow[d4];
        a += wv.x*gv.x + wv.y*gv.y + wv.z*gv.z + wv.w*gv.w;
    }
    hc[t] = a / ls[h];
    __syncthreads();

    const float4* worow = (const float4*)(Wo + (size_t)t * DIM);
    float o = 0.f;
    #pragma unroll 8
    for (int i4 = 0; i4 < 64; ++i4) {
        float4 wv = worow[i4]; float4 hv = ((const float4*)hc)[i4];
        o += wv.x*hv.x + wv.y*hv.y + wv.z*hv.z + wv.w*hv.w;
    }
    out[(size_t)b * DIM + t] = o;
}

extern "C" void kernel_launch(void* const* d_in, const int* in_sizes, int n_in,
                              void* d_out, int out_size, void* d_ws, size_t ws_size,
                              hipStream_t stream) {
    const float* ctx  = (const float*)d_in[0];
    const float* node = (const float*)d_in[1];
    const void*  mask = (const void*)d_in[2];
    const float* Wq   = (const float*)d_in[3];
    const float* Wk   = (const float*)d_in[4];
    const float* Wv   = (const float*)d_in[5];
    const float* Wo   = (const float*)d_in[6];
    float* out = (float*)d_out;

    // ws floats: flag/pad 256 | wt 131072 | gred 131072 | lred 512 | partials
    const size_t FIX = 256 + (size_t)NB*NH*DIM * 2 + 512;
    int lgnp = 5;  // npart=32 -> 1024 blocks (4/CU)
    {
        size_t need = (FIX + (size_t)NB * 32 * PREC2) * 4;
        if (ws_size < need) lgnp = 4;
    }
    int npart = 1 << lgnp;
    int psz = (NN + npart - 1) / npart;

    float* wsf = (float*)d_ws;
    int*   flag = (int*)d_ws;
    float* wt = wsf + 256;
    float* gred = wt + (size_t)NB * NH * DIM;
    float* lred = gred + (size_t)NB * NH * DIM;
    float* partials = lred + 512;

    hipMemsetAsync(flag, 0, 4, stream);
    detect_mask_kernel<<<64, 256, 0, stream>>>((const int*)mask, flag);
    prep_kernel<<<NB, 256, 0, stream>>>(ctx, Wq, Wk, wt);
    attend_kernel<<<NB * npart, 256, 0, stream>>>(node, mask, wt, partials, flag, lgnp, psz);
    reduce_kernel<<<NB * 16, 256, 0, stream>>>(partials, gred, lred, lgnp);
    output_kernel<<<NB, 256, 0, stream>>>(gred, lred, Wv, Wo, out);
}

// Round 7
// 132.075 us; speedup vs baseline: 3.9287x; 1.3519x over previous
//
#include <hip/hip_runtime.h>
#include <math.h>

#define NB 32
#define NN 10000
#define DIM 256
#define NH 16
#define PREC2 4112   // per-block partial: l[16] + g[16*256]

typedef short short8v __attribute__((ext_vector_type(8)));
typedef float float4v __attribute__((ext_vector_type(4)));

// ---- bf16 helpers (RNE pack) ----
__device__ __forceinline__ unsigned bf16rne(float f) {
    unsigned u = __float_as_uint(f);
    return (u + 0x7FFFu + ((u >> 16) & 1u)) >> 16;
}
__device__ __forceinline__ unsigned pack2(float a, float b) {
    return bf16rne(a) | (bf16rne(b) << 16);
}
__device__ __forceinline__ short8v pack8(float4 A, float4 B) {
    union { short8v s; unsigned u[4]; } r;
    r.u[0] = pack2(A.x, A.y); r.u[1] = pack2(A.z, A.w);
    r.u[2] = pack2(B.x, B.y); r.u[3] = pack2(B.z, B.w);
    return r.s;
}
// row-parity XOR swizzle for XT (128B rows): spreads row-strided access across banks
#define SWB(d) ((((d) >> 1) & 7) << 4)

// ---------------- kernel 0: detect mask dtype (int32 vs uint8) --------------
__global__ void detect_mask_kernel(const int* mask_i, int* flag) {
    int bad = 0;
    for (int i = blockIdx.x * 256 + threadIdx.x; i < 80000; i += gridDim.x * 256)
        if ((unsigned)mask_i[i] > 1u) bad = 1;
    if (bad) atomicOr(flag, 1);
}

// ---------------- kernel 1a: q[b,i] = dot(ctx[b,:], Wq[i,:]) ----------------
__global__ void prep_q_kernel(const float* __restrict__ ctx,
                              const float* __restrict__ Wq,
                              float* __restrict__ qws) {
    int b = blockIdx.x >> 2, iq = blockIdx.x & 3;
    int t = threadIdx.x, lane = t & 63, w = t >> 6;
    __shared__ float ctxL[DIM];
    ctxL[t] = ctx[b * DIM + t];
    __syncthreads();
    float4 c = ((const float4*)ctxL)[lane];
    for (int i = iq * 64 + w; i < iq * 64 + 64; i += 4) {
        float4 wq = ((const float4*)(Wq + (size_t)i * DIM))[lane];
        float s = wq.x * c.x + wq.y * c.y + wq.z * c.z + wq.w * c.w;
        #pragma unroll
        for (int off = 1; off < 64; off <<= 1) s += __shfl_xor(s, off, 64);
        if (lane == 0) qws[b * DIM + i] = s;
    }
}

// ---------------- kernel 1b: w~[b,h,d] = 0.25 * sum_j q[h*16+j] Wk[h*16+j,d]
__global__ void prep_wt_kernel(const float* __restrict__ qws,
                               const float* __restrict__ Wk,
                               float* __restrict__ wt) {
    int b = blockIdx.x >> 2, dq = blockIdx.x & 3;
    int t = threadIdx.x;
    int d = dq * 64 + (t & 63);
    int hg = t >> 6;
    #pragma unroll
    for (int hh = 0; hh < 4; ++hh) {
        int h = hg * 4 + hh;
        float a = 0.f;
        #pragma unroll
        for (int j = 0; j < 16; ++j)
            a += qws[b * DIM + h * 16 + j] * Wk[(size_t)(h * 16 + j) * DIM + d];
        wt[((size_t)b * NH + h) * DIM + d] = 0.25f * a;
    }
}

// ---------------- kernel 2: MFMA attend, single global-x read ---------------
// Per 64-node tile:
//  phase A (wave = 16 nodes): reads x rows fp32 from GLOBAL (only reader),
//    packs bf16 fragments, scatters them into XT[d][node] (b16, swizzled),
//    8x mfma_16x16x32_bf16 vs hoisted w~ frags -> S; p = mask*exp(S);
//    l partial via 2 shfl; P -> LDS [h][node] bf16.
//  phase B (wave = 64 d-cols): G^T += X^T . P^T via 8x MFMA from XT/PL.
__launch_bounds__(256, 4)
__global__ void attend_kernel(const float* __restrict__ node,
                              const void* __restrict__ maskp,
                              const float* __restrict__ wt,
                              float* __restrict__ partials,
                              const int* __restrict__ flag,
                              int lgnp, int psz) {
    __shared__ __align__(16) char smem[35328];  // XT 32768 | PL 2304 | LL 256
    char* XT = smem;
    char* PL = smem + 32768;
    float* LL = (float*)(smem + 35072);

    int npart = 1 << lgnp;
    int b = blockIdx.x >> lgnp;
    int part = blockIdx.x & (npart - 1);
    int t = threadIdx.x, lane = t & 63;
    int w = __builtin_amdgcn_readfirstlane(t >> 6);
    int hq = lane & 15, g = lane >> 4;
    const bool bytemask = (*flag != 0);

    int n0 = part * psz;
    int n1 = n0 + psz; if (n1 > NN) n1 = NN;
    const float* nb = node + (size_t)b * NN * DIM;
    const unsigned char* m8 = (const unsigned char*)maskp + (size_t)b * NN;
    const int* m32 = (const int*)maskp + (size_t)b * NN;

    // hoist w~ B-fragments (once per block)
    short8v wfrag[8];
    {
        const float* wrow = wt + ((size_t)b * NH + hq) * DIM + g * 8;
        #pragma unroll
        for (int cc = 0; cc < 8; ++cc) {
            float4 A = *(const float4*)(wrow + cc * 32);
            float4 B = *(const float4*)(wrow + cc * 32 + 4);
            wfrag[cc] = pack8(A, B);
        }
    }

    float4v accB[4];
    #pragma unroll
    for (int m = 0; m < 4; ++m) accB[m] = (float4v){0.f, 0.f, 0.f, 0.f};
    float lacc = 0.f;

    int ln2 = (16 * w + hq) * 2;   // XT byte-column of this lane's node

    for (int tb = n0; tb < n1; tb += 64) {
        __syncthreads();   // prev phase B done: XT/PL reusable

        // ---- phase A: global fp32 rows -> bf16 frags -> (XT scatter + MFMA)
        float4v acc = (float4v){0.f, 0.f, 0.f, 0.f};
        {
            int anode = tb + 16 * w + hq;
            if (anode > NN - 1) anode = NN - 1;
            const float* arow = nb + (size_t)anode * DIM + g * 8;
            #pragma unroll
            for (int cc = 0; cc < 8; ++cc) {
                float4 A = *(const float4*)(arow + cc * 32);
                float4 B = *(const float4*)(arow + cc * 32 + 4);
                short8v af = pack8(A, B);
                union { short8v s; unsigned short u[8]; } U; U.s = af;
                int d0 = g * 8 + cc * 32;
                #pragma unroll
                for (int j = 0; j < 8; ++j)
                    *(unsigned short*)(XT + (size_t)(d0 + j) * 128 +
                                       (ln2 ^ SWB(d0 + j))) = U.u[j];
                acc = __builtin_amdgcn_mfma_f32_16x16x32_bf16(af, wfrag[cc], acc, 0, 0, 0);
            }
        }
        // mask + exp ; D-layout: lane holds head hq, nodes (4g + r)
        int mb = tb + 16 * w + 4 * g;
        float mv0, mv1, mv2, mv3;
        {
            int mc = mb > NN - 4 ? NN - 4 : mb;
            if (bytemask) {
                uchar4 mm = *(const uchar4*)(m8 + mc);
                mv0 = mm.x; mv1 = mm.y; mv2 = mm.z; mv3 = mm.w;
            } else {
                int4 mm = *(const int4*)(m32 + mc);
                mv0 = (mm.x != 0); mv1 = (mm.y != 0); mv2 = (mm.z != 0); mv3 = (mm.w != 0);
            }
        }
        if (mb + 0 >= n1) mv0 = 0.f;
        if (mb + 1 >= n1) mv1 = 0.f;
        if (mb + 2 >= n1) mv2 = 0.f;
        if (mb + 3 >= n1) mv3 = 0.f;
        // logits ~N(0,1): exp safe in fp32
        float p0 = mv0 * __expf(acc[0]);
        float p1 = mv1 * __expf(acc[1]);
        float p2 = mv2 * __expf(acc[2]);
        float p3 = mv3 * __expf(acc[3]);
        float ts = p0 + p1 + p2 + p3;
        ts += __shfl_xor(ts, 16, 64);
        ts += __shfl_xor(ts, 32, 64);
        lacc += ts;
        *(uint2*)(PL + hq * 144 + (16 * w + 4 * g) * 2) =
            make_uint2(pack2(p0, p1), pack2(p2, p3));

        __syncthreads();   // XT + PL ready

        // ---- phase B: G^T[d][h] += X^T . P^T ; wave owns d = 64w..64w+63 ----
        #pragma unroll
        for (int chunk = 0; chunk < 2; ++chunk) {
            short8v pf = *(const short8v*)(PL + hq * 144 + chunk * 64 + g * 16);
            #pragma unroll
            for (int m = 0; m < 4; ++m) {
                int d = 64 * w + 16 * m + hq;
                short8v xf = *(const short8v*)(XT + (size_t)d * 128 +
                                               ((chunk * 64 + g * 16) ^ SWB(d)));
                accB[m] = __builtin_amdgcn_mfma_f32_16x16x32_bf16(xf, pf, accB[m], 0, 0, 0);
            }
        }
    }

    // ---- epilogue: bounce G through LDS for coalesced partial write ----
    __syncthreads();
    float* GL = (float*)smem;                      // [16][260] f32, reuses XT
    #pragma unroll
    for (int m = 0; m < 4; ++m) {
        #pragma unroll
        for (int r = 0; r < 4; ++r)
            GL[hq * 260 + 64 * w + 16 * m + 4 * g + r] = accB[m][r];
    }
    if (lane < 16) LL[w * 16 + lane] = lacc;
    __syncthreads();

    float* rec = partials + (size_t)blockIdx.x * PREC2;
    if (t < NH) rec[t] = LL[t] + LL[16 + t] + LL[32 + t] + LL[48 + t];
    for (int i = t; i < NH * DIM; i += 256)
        rec[16 + i] = GL[(i >> 8) * 260 + (i & 255)];
}

// ---------------- kernel 3a: merge partials (coalesced) ---------------------
__global__ void reduce_kernel(const float* __restrict__ partials,
                              float* __restrict__ gred,
                              float* __restrict__ lred, int lgnp) {
    int npart = 1 << lgnp;
    int b = blockIdx.x >> 4, c = blockIdx.x & 15;
    int e = c * 256 + threadIdx.x;            // h*256 + d
    const float* pb = partials + ((size_t)b << lgnp) * PREC2;
    float a = 0.f;
    for (int p = 0; p < npart; ++p) a += pb[(size_t)p * PREC2 + 16 + e];
    gred[(size_t)b * (NH * DIM) + e] = a;
    if (c == 0 && threadIdx.x < NH) {
        float la = 0.f;
        for (int p = 0; p < npart; ++p) la += pb[(size_t)p * PREC2 + threadIdx.x];
        lred[b * NH + threadIdx.x] = la;
    }
}

// ---------------- kernel 3b: hc[b,i] = dot(Wv[i,:], g[h(i),:]) / l[h(i)] ----
__global__ void hc_kernel(const float* __restrict__ gred,
                          const float* __restrict__ lred,
                          const float* __restrict__ Wv,
                          float* __restrict__ hcws) {
    int b = blockIdx.x >> 3, o = blockIdx.x & 7;
    int t = threadIdx.x;
    int i = o * 32 + (t >> 3), sub = t & 7;
    int h = i >> 4;
    const float4* wrow = (const float4*)(Wv + (size_t)i * DIM + sub * 32);
    const float4* grow = (const float4*)(gred + (size_t)b * NH * DIM + h * DIM + sub * 32);
    float a = 0.f;
    #pragma unroll
    for (int k = 0; k < 8; ++k) {
        float4 wv = wrow[k], gv = grow[k];
        a += wv.x * gv.x + wv.y * gv.y + wv.z * gv.z + wv.w * gv.w;
    }
    a += __shfl_xor(a, 1, 64);
    a += __shfl_xor(a, 2, 64);
    a += __shfl_xor(a, 4, 64);
    if (sub == 0) hcws[b * DIM + i] = a / lred[b * NH + h];
}

// ---------------- kernel 3c: out[b,e] = dot(hc[b,:], Wo[e,:]) ---------------
__global__ void out_kernel(const float* __restrict__ hcws,
                           const float* __restrict__ Wo,
                           float* __restrict__ out) {
    int b = blockIdx.x >> 3, o = blockIdx.x & 7;
    int t = threadIdx.x;
    int e = o * 32 + (t >> 3), sub = t & 7;
    const float4* wrow = (const float4*)(Wo + (size_t)e * DIM + sub * 32);
    const float4* hrow = (const float4*)(hcws + (size_t)b * DIM + sub * 32);
    float a = 0.f;
    #pragma unroll
    for (int k = 0; k < 8; ++k) {
        float4 wv = wrow[k], hv = hrow[k];
        a += wv.x * hv.x + wv.y * hv.y + wv.z * hv.z + wv.w * hv.w;
    }
    a += __shfl_xor(a, 1, 64);
    a += __shfl_xor(a, 2, 64);
    a += __shfl_xor(a, 4, 64);
    if (sub == 0) out[(size_t)b * DIM + e] = a;
}

extern "C" void kernel_launch(void* const* d_in, const int* in_sizes, int n_in,
                              void* d_out, int out_size, void* d_ws, size_t ws_size,
                              hipStream_t stream) {
    const float* ctx  = (const float*)d_in[0];
    const float* node = (const float*)d_in[1];
    const void*  mask = (const void*)d_in[2];
    const float* Wq   = (const float*)d_in[3];
    const float* Wk   = (const float*)d_in[4];
    const float* Wv   = (const float*)d_in[5];
    const float* Wo   = (const float*)d_in[6];
    float* out = (float*)d_out;

    // ws floats: flag 256 | wt 131072 | gred 131072 | lred 512 | qws 8192 |
    //            hcws 8192 | partials NB*npart*PREC2
    const size_t FIX = 256 + (size_t)NB*NH*DIM * 2 + 512 + 8192 + 8192;
    int lgnp = 5;  // npart=32 -> 1024 blocks (4/CU)
    {
        size_t need = (FIX + (size_t)NB * 32 * PREC2) * 4;
        if (ws_size < need) lgnp = 4;
    }
    int npart = 1 << lgnp;
    int psz = (NN + npart - 1) / npart;

    float* wsf = (float*)d_ws;
    int*   flag = (int*)d_ws;
    float* wt = wsf + 256;
    float* gred = wt + (size_t)NB * NH * DIM;
    float* lred = gred + (size_t)NB * NH * DIM;
    float* qws = lred + 512;
    float* hcws = qws + 8192;
    float* partials = hcws + 8192;

    hipMemsetAsync(flag, 0, 4, stream);
    detect_mask_kernel<<<64, 256, 0, stream>>>((const int*)mask, flag);
    prep_q_kernel<<<NB * 4, 256, 0, stream>>>(ctx, Wq, qws);
    prep_wt_kernel<<<NB * 4, 256, 0, stream>>>(qws, Wk, wt);
    attend_kernel<<<NB * npart, 256, 0, stream>>>(node, mask, wt, partials, flag, lgnp, psz);
    reduce_kernel<<<NB * 16, 256, 0, stream>>>(partials, gred, lred, lgnp);
    hc_kernel<<<NB * 8, 256, 0, stream>>>(gred, lred, Wv, hcws);
    out_kernel<<<NB * 8, 256, 0, stream>>>(hcws, Wo, out);
}